// Round 1
// baseline (1793.224 us; speedup 1.0000x reference)
//
#include <hip/hip_runtime.h>

// GCN 2-layer: x[N,128] @ W1[128,64] -> gcn_conv -> relu -> @ W2[64,40] -> gcn_conv -> relu
// N = 100000, E = 1600000 (derived from in_sizes at launch).

#define F0 128
#define F1 64
#define F2 40

// ---------------- init: zero agg1 + out, deg = 1.0 (self-loop) ----------------
__global__ void k_init(float* __restrict__ deg, float* __restrict__ agg1,
                       float* __restrict__ out, int n) {
    const int total = n * F1;          // largest buffer (n*64)
    const int n40 = n * F2;
    const int stride = gridDim.x * blockDim.x;
    for (int i = blockIdx.x * blockDim.x + threadIdx.x; i < total; i += stride) {
        agg1[i] = 0.f;
        if (i < n40) out[i] = 0.f;
        if (i < n) deg[i] = 1.0f;
    }
}

// ---------------- degree count (dst occurrences) ----------------
__global__ void k_deg(const int* __restrict__ ei, float* __restrict__ deg, int E) {
    const int stride = gridDim.x * blockDim.x;
    for (int e = blockIdx.x * blockDim.x + threadIdx.x; e < E; e += stride)
        atomicAdd(&deg[ei[E + e]], 1.0f);
}

// ---------------- deg -> rsqrt(deg) in place ----------------
__global__ void k_rsqrt(float* __restrict__ deg, int n) {
    const int i = blockIdx.x * blockDim.x + threadIdx.x;
    if (i < n) deg[i] = rsqrtf(deg[i]);
}

// ---------------- gemm1: h[N,64] = x[N,128] @ W[128,64] ----------------
// 256 threads: col = tid&63 (W column in 128 VGPRs), 4 row-quads, 8 rows/thread,
// 32-row x tile staged in LDS, broadcast float4 reads.
__global__ __launch_bounds__(256) void k_gemm1(const float* __restrict__ x,
                                               const float* __restrict__ W,
                                               float* __restrict__ h, int n) {
    __shared__ float xs[32 * F0];
    const int tid = threadIdx.x;
    const int c = tid & 63;
    const int rq = tid >> 6;

    float w[F0];
#pragma unroll
    for (int k = 0; k < F0; ++k) w[k] = W[k * F1 + c];

    const int ntiles = (n + 31) >> 5;
    for (int tile = blockIdx.x; tile < ntiles; tile += gridDim.x) {
        // stage 32 rows (4096 floats = 1024 float4) into LDS
        float4* xs4w = (float4*)xs;
#pragma unroll
        for (int j = 0; j < 4; ++j) {
            int fi = j * 256 + tid;            // float4 index within tile
            int row = fi >> 5;                 // 32 float4 per row
            int rg = tile * 32 + row;
            if (rg > n - 1) rg = n - 1;        // clamp (tail safety)
            const float4* xrow = (const float4*)(x + (long long)rg * F0);
            xs4w[fi] = xrow[fi & 31];
        }
        __syncthreads();

        float acc[8] = {0.f,0.f,0.f,0.f,0.f,0.f,0.f,0.f};
#pragma unroll
        for (int b = 0; b < 32; ++b) {
            const float w0 = w[4*b+0], w1 = w[4*b+1], w2 = w[4*b+2], w3 = w[4*b+3];
#pragma unroll
            for (int i = 0; i < 8; ++i) {
                float4 xv = ((const float4*)xs)[(rq * 8 + i) * 32 + b];
                acc[i] = fmaf(xv.w, w3, fmaf(xv.z, w2, fmaf(xv.y, w1, fmaf(xv.x, w0, acc[i]))));
            }
        }

#pragma unroll
        for (int i = 0; i < 8; ++i) {
            int rg = tile * 32 + rq * 8 + i;
            if (rg < n) h[(long long)rg * F1 + c] = acc[i];
        }
        __syncthreads();
    }
}

// ---------------- gemm2: h[N,40] = x[N,64] @ W[64,40] ----------------
__global__ __launch_bounds__(256) void k_gemm2(const float* __restrict__ x,
                                               const float* __restrict__ W,
                                               float* __restrict__ h, int n) {
    __shared__ float xs[32 * F1];
    const int tid = threadIdx.x;
    const int c = tid & 63;
    const int rq = tid >> 6;

    float w[F1];
    if (c < F2) {
#pragma unroll
        for (int k = 0; k < F1; ++k) w[k] = W[k * F2 + c];
    } else {
#pragma unroll
        for (int k = 0; k < F1; ++k) w[k] = 0.f;
    }

    const int ntiles = (n + 31) >> 5;
    for (int tile = blockIdx.x; tile < ntiles; tile += gridDim.x) {
        float4* xs4w = (float4*)xs;
#pragma unroll
        for (int j = 0; j < 2; ++j) {
            int fi = j * 256 + tid;            // 512 float4 total
            int row = fi >> 4;                 // 16 float4 per row
            int rg = tile * 32 + row;
            if (rg > n - 1) rg = n - 1;
            const float4* xrow = (const float4*)(x + (long long)rg * F1);
            xs4w[fi] = xrow[fi & 15];
        }
        __syncthreads();

        float acc[8] = {0.f,0.f,0.f,0.f,0.f,0.f,0.f,0.f};
#pragma unroll
        for (int b = 0; b < 16; ++b) {
            const float w0 = w[4*b+0], w1 = w[4*b+1], w2 = w[4*b+2], w3 = w[4*b+3];
#pragma unroll
            for (int i = 0; i < 8; ++i) {
                float4 xv = ((const float4*)xs)[(rq * 8 + i) * 16 + b];
                acc[i] = fmaf(xv.w, w3, fmaf(xv.z, w2, fmaf(xv.y, w1, fmaf(xv.x, w0, acc[i]))));
            }
        }

        if (c < F2) {
#pragma unroll
            for (int i = 0; i < 8; ++i) {
                int rg = tile * 32 + rq * 8 + i;
                if (rg < n) h[(long long)rg * F2 + c] = acc[i];
            }
        }
        __syncthreads();
    }
}

// ---------------- scatter1: agg1[dst,:64] += h1[src,:64] * norm ----------------
__global__ void k_scatter1(const int* __restrict__ ei, const float* __restrict__ invs,
                           const float* __restrict__ h, float* __restrict__ agg, int E) {
    const int t = blockIdx.x * blockDim.x + threadIdx.x;
    const int lane = t & 63;
    const int e = t >> 6;
    if (e >= E) return;
    const int s = ei[e];
    const int d = ei[E + e];
    const float nrm = invs[s] * invs[d];
    atomicAdd(&agg[(long long)d * F1 + lane], h[(long long)s * F1 + lane] * nrm);
}

// ---------------- scatter2: out[dst,:40] += h2[src,:40] * norm ----------------
__global__ void k_scatter2(const int* __restrict__ ei, const float* __restrict__ invs,
                           const float* __restrict__ h, float* __restrict__ agg, int E) {
    const int t = blockIdx.x * blockDim.x + threadIdx.x;
    const int lane = t & 63;
    const int e = t >> 6;
    if (e >= E) return;
    const int s = ei[e];
    const int d = ei[E + e];
    const float nrm = invs[s] * invs[d];
    if (lane < F2)
        atomicAdd(&agg[(long long)d * F2 + lane], h[(long long)s * F2 + lane] * nrm);
}

// ---------------- self-loop + relu, layer 1 (in place into h1) ----------------
__global__ void k_self1(const float* __restrict__ agg, float* __restrict__ h,
                        const float* __restrict__ invs, int n) {
    const int i = blockIdx.x * blockDim.x + threadIdx.x;
    if (i >= n * F1) return;
    const int r = i >> 6;
    const float iv = invs[r];
    h[i] = fmaxf(agg[i] + h[i] * iv * iv, 0.f);
}

// ---------------- self-loop + relu, layer 2 (out in place) ----------------
__global__ void k_self2(float* __restrict__ out, const float* __restrict__ h,
                        const float* __restrict__ invs, int n) {
    const int i = blockIdx.x * blockDim.x + threadIdx.x;
    if (i >= n * F2) return;
    const int r = i / F2;
    const float iv = invs[r];
    out[i] = fmaxf(out[i] + h[i] * iv * iv, 0.f);
}

extern "C" void kernel_launch(void* const* d_in, const int* in_sizes, int n_in,
                              void* d_out, int out_size, void* d_ws, size_t ws_size,
                              hipStream_t stream) {
    const float* x  = (const float*)d_in[0];
    const int*   ei = (const int*)d_in[1];
    const float* W1 = (const float*)d_in[2];
    const float* W2 = (const float*)d_in[3];
    float* out = (float*)d_out;
    const int n = in_sizes[0] / F0;     // 100000
    const int E = in_sizes[1] / 2;      // 1600000

    // workspace layout (floats): deg | h1[n*64] | agg1[n*64] | h2[n*40]
    float* ws = (float*)d_ws;
    size_t o = 0;
    float* deg  = ws + o; o += ((size_t)n + 63) & ~(size_t)63;
    float* h1   = ws + o; o += (size_t)n * F1;
    float* agg1 = ws + o; o += (size_t)n * F1;
    float* h2   = ws + o; // + n*F2

    const int ntiles = (n + 31) / 32;
    const int gscat = (int)(((long long)E * 64 + 255) / 256);

    hipLaunchKernelGGL(k_init,   dim3(2048),  dim3(256), 0, stream, deg, agg1, out, n);
    hipLaunchKernelGGL(k_deg,    dim3(2048),  dim3(256), 0, stream, ei, deg, E);
    hipLaunchKernelGGL(k_rsqrt,  dim3((n + 255) / 256), dim3(256), 0, stream, deg, n);

    hipLaunchKernelGGL(k_gemm1,  dim3(ntiles), dim3(256), 0, stream, x, W1, h1, n);
    hipLaunchKernelGGL(k_scatter1, dim3(gscat), dim3(256), 0, stream, ei, deg, h1, agg1, E);
    hipLaunchKernelGGL(k_self1,  dim3((n * F1 + 255) / 256), dim3(256), 0, stream, agg1, h1, deg, n);

    hipLaunchKernelGGL(k_gemm2,  dim3(ntiles), dim3(256), 0, stream, h1, W2, h2, n);
    hipLaunchKernelGGL(k_scatter2, dim3(gscat), dim3(256), 0, stream, ei, deg, h2, out, E);
    hipLaunchKernelGGL(k_self2,  dim3((n * F2 + 255) / 256), dim3(256), 0, stream, out, h2, deg, n);
}